// Round 1
// baseline (664.247 us; speedup 1.0000x reference)
//
#include <hip/hip_runtime.h>

#define NN 23552   // total nodes
#define BBATCH 1024
#define PP 23      // nodes per frame
#define FF 14
#define DD 256
#define HHEADS 4
#define DHH 64
#define CC 23

// ---------------- input projection: h = x @ W_in + b_in ----------------
__global__ __launch_bounds__(256) void k_in_proj(const float* __restrict__ x,
    const float* __restrict__ Win, const float* __restrict__ bin,
    float* __restrict__ h)
{
    __shared__ float xs[16][FF];
    int t = threadIdx.x;
    int r0 = blockIdx.x * 16;
    for (int idx = t; idx < 16 * FF; idx += 256) {
        int r = idx / FF, f = idx - r * FF;
        xs[r][f] = x[(r0 + r) * FF + f];
    }
    __syncthreads();
    float w[FF];
#pragma unroll
    for (int f = 0; f < FF; ++f) w[f] = Win[f * DD + t];
    float bb = bin[t];
#pragma unroll
    for (int r = 0; r < 16; ++r) {
        float acc = bb;
#pragma unroll
        for (int f = 0; f < FF; ++f) acc = fmaf(xs[r][f], w[f], acc);
        h[(r0 + r) * DD + t] = acc;
    }
}

// ---------------- per-layer projections: hl = h@Wl, hr = h@Wr ----------------
__global__ __launch_bounds__(256) void k_proj(const float* __restrict__ h,
    const float* __restrict__ Wl, const float* __restrict__ Wr,
    float* __restrict__ hl, float* __restrict__ hr)
{
    __shared__ __align__(16) float hs[16][DD];
    int t = threadIdx.x;
    int r0 = blockIdx.x * 16;
    for (int idx = t * 4; idx < 16 * DD; idx += 1024) {
        *(float4*)(&hs[0][0] + idx) = *(const float4*)(h + (size_t)r0 * DD + idx);
    }
    __syncthreads();
    float accl[16], accr[16];
#pragma unroll
    for (int r = 0; r < 16; ++r) { accl[r] = 0.f; accr[r] = 0.f; }
    for (int k0 = 0; k0 < DD; k0 += 4) {
        float wl0 = Wl[(k0 + 0) * DD + t], wl1 = Wl[(k0 + 1) * DD + t];
        float wl2 = Wl[(k0 + 2) * DD + t], wl3 = Wl[(k0 + 3) * DD + t];
        float wr0 = Wr[(k0 + 0) * DD + t], wr1 = Wr[(k0 + 1) * DD + t];
        float wr2 = Wr[(k0 + 2) * DD + t], wr3 = Wr[(k0 + 3) * DD + t];
#pragma unroll
        for (int r = 0; r < 16; ++r) {
            float4 hv = *(const float4*)(&hs[r][k0]);
            accl[r] = fmaf(hv.x, wl0, accl[r]);
            accl[r] = fmaf(hv.y, wl1, accl[r]);
            accl[r] = fmaf(hv.z, wl2, accl[r]);
            accl[r] = fmaf(hv.w, wl3, accl[r]);
            accr[r] = fmaf(hv.x, wr0, accr[r]);
            accr[r] = fmaf(hv.y, wr1, accr[r]);
            accr[r] = fmaf(hv.z, wr2, accr[r]);
            accr[r] = fmaf(hv.w, wr3, accr[r]);
        }
    }
#pragma unroll
    for (int r = 0; r < 16; ++r) {
        hl[(size_t)(r0 + r) * DD + t] = accl[r];
        hr[(size_t)(r0 + r) * DD + t] = accr[r];
    }
}

// ---------------- dense per-frame GATv2 attention (complete digraph) ----------------
// scores S[i][j][h] = att_h . leakyrelu(hl[j] + hr[i]); softmax over j != i;
// h[i] = elu(sum_j alpha[i][j] * hl[j] + h[i])
__global__ __launch_bounds__(256) void k_edges(const float* __restrict__ hl,
    const float* __restrict__ hr, const float* __restrict__ att,
    float* __restrict__ h)
{
    __shared__ float sl[PP][DD + 1];
    __shared__ float sr[PP][DD + 1];
    __shared__ float S[PP][PP][HHEADS];
    __shared__ float satt[DD];
    int t = threadIdx.x;
    int base = blockIdx.x * PP;

    satt[t] = att[t];
    for (int idx = t; idx < PP * DD; idx += 256) {
        int r = idx >> 8, c = idx & 255;
        sl[r][c] = hl[(size_t)(base + r) * DD + c];
        sr[r][c] = hr[(size_t)(base + r) * DD + c];
    }
    __syncthreads();

    // scores: one thread per (dst i, src j) pair, all 4 heads
    for (int p = t; p < PP * PP; p += 256) {
        int i = p / PP;            // dst
        int j = p - i * PP;        // src
        float acch[HHEADS];
#pragma unroll
        for (int hh = 0; hh < HHEADS; ++hh) {
            float a = 0.f;
#pragma unroll
            for (int k = 0; k < DHH; ++k) {
                int c = hh * DHH + k;
                float v = sl[j][c] + sr[i][c];
                v = (v >= 0.f) ? v : 0.2f * v;
                a = fmaf(satt[c], v, a);
            }
            acch[hh] = a;
        }
#pragma unroll
        for (int hh = 0; hh < HHEADS; ++hh)
            S[i][j][hh] = (i == j) ? -1e30f : acch[hh];
    }
    __syncthreads();

    // softmax over sources j for each (i, head)
    if (t < PP * HHEADS) {
        int i = t >> 2, hh = t & 3;
        float m = -1e30f;
#pragma unroll
        for (int j = 0; j < PP; ++j) m = fmaxf(m, S[i][j][hh]);
        float e[PP];
        float ssum = 0.f;
#pragma unroll
        for (int j = 0; j < PP; ++j) {
            float ev = expf(S[i][j][hh] - m);
            e[j] = ev;
            ssum += ev;
        }
        float inv = 1.f / ssum;
#pragma unroll
        for (int j = 0; j < PP; ++j) S[i][j][hh] = e[j] * inv;
    }
    __syncthreads();

    // aggregate + residual + elu, in-place on h
    int hh = t >> 6;   // head is constant within each wave
    for (int i = 0; i < PP; ++i) {
        float acc = 0.f;
#pragma unroll
        for (int j = 0; j < PP; ++j) acc = fmaf(S[i][j][hh], sl[j][t], acc);
        size_t gi = (size_t)(base + i) * DD + t;
        float res = acc + h[gi];
        h[gi] = (res > 0.f) ? res : expm1f(res);
    }
}

// ---------------- mean readout per frame ----------------
__global__ __launch_bounds__(256) void k_readout(const float* __restrict__ h,
    float* __restrict__ g)
{
    int b = blockIdx.x, t = threadIdx.x;
    const float* hp = h + (size_t)b * PP * DD + t;
    float acc = 0.f;
#pragma unroll
    for (int p = 0; p < PP; ++p) acc += hp[p * DD];
    g[b * DD + t] = acc * (1.0f / 23.0f);
}

// ---------------- EB[c] = E_recv[c] @ Ws1[256:512,:]  (graph-independent) ----------------
__global__ __launch_bounds__(256) void k_eb(const float* __restrict__ E,
    const float* __restrict__ Ws1, float* __restrict__ EB)
{
    int c = blockIdx.x, t = threadIdx.x;
    float acc = 0.f;
    for (int k = 0; k < DD; ++k)
        acc = fmaf(E[c * DD + k], Ws1[(DD + k) * DD + t], acc);
    EB[c * DD + t] = acc;
}

// ---------------- per-graph head: recv softmax + marginalized shot logit ----------------
__global__ __launch_bounds__(256) void k_head(const float* __restrict__ g,
    const float* __restrict__ Wr1, const float* __restrict__ br1,
    const float* __restrict__ Wr2, const float* __restrict__ br2,
    const float* __restrict__ Ws1, const float* __restrict__ bs1,
    const float* __restrict__ Ws2, const float* __restrict__ bs2,
    const float* __restrict__ EB, float* __restrict__ out)
{
    __shared__ float gs[DD], t1[DD], gtop[DD], logits[CC], probs[CC], red[4];
    int b = blockIdx.x, t = threadIdx.x;
    gs[t] = g[b * DD + t];
    __syncthreads();

    float a1 = 0.f, a2 = 0.f;
    for (int k = 0; k < DD; ++k) {
        float gv = gs[k];
        a1 = fmaf(gv, Wr1[k * DD + t], a1);
        a2 = fmaf(gv, Ws1[k * DD + t], a2);   // rows 0..255 of Ws1 (g part)
    }
    t1[t] = fmaxf(a1 + br1[t], 0.f);
    gtop[t] = a2 + bs1[t];
    __syncthreads();

    if (t < CC) {
        float acc = br2[t];
        for (int d = 0; d < DD; ++d) acc = fmaf(t1[d], Wr2[d * CC + t], acc);
        logits[t] = acc;
    }
    __syncthreads();
    if (t < CC) {
        float m = -1e30f;
        for (int c = 0; c < CC; ++c) m = fmaxf(m, logits[c]);
        float s = 0.f;
        for (int c = 0; c < CC; ++c) s += expf(logits[c] - m);
        probs[t] = expf(logits[t] - m) / s;
    }
    __syncthreads();

    // sum_c probs[c] * (relu(gtop + EB[c]) . Ws2) + bs2
    float wd = Ws2[t];
    float gt = gtop[t];
    float acc = 0.f;
#pragma unroll
    for (int c = 0; c < CC; ++c) {
        float s1 = fmaxf(gt + EB[c * DD + t], 0.f);
        acc = fmaf(probs[c], s1, acc);
    }
    acc *= wd;
#pragma unroll
    for (int off = 32; off > 0; off >>= 1) acc += __shfl_down(acc, off, 64);
    if ((t & 63) == 0) red[t >> 6] = acc;
    __syncthreads();
    if (t == 0) out[b] = red[0] + red[1] + red[2] + red[3] + bs2[0];
}

extern "C" void kernel_launch(void* const* d_in, const int* in_sizes, int n_in,
                              void* d_out, int out_size, void* d_ws, size_t ws_size,
                              hipStream_t stream)
{
    const float* x     = (const float*)d_in[0];
    // d_in[1] = edge_index, d_in[2] = batch: structure is fixed (complete
    // digraph per 23-node frame), handled implicitly.
    const float* Win   = (const float*)d_in[3];
    const float* bin   = (const float*)d_in[4];
    const float* Wl    = (const float*)d_in[5];   // [3,256,256] per-layer row-major
    const float* Wr    = (const float*)d_in[6];
    const float* att   = (const float*)d_in[7];   // [3,256]
    const float* Wr1   = (const float*)d_in[8];
    const float* br1   = (const float*)d_in[9];
    const float* Wr2   = (const float*)d_in[10];
    const float* br2   = (const float*)d_in[11];
    const float* Erecv = (const float*)d_in[12];
    const float* Ws1   = (const float*)d_in[13];  // [512,256]
    const float* bs1   = (const float*)d_in[14];
    const float* Ws2   = (const float*)d_in[15];  // [256,1]
    const float* bs2   = (const float*)d_in[16];
    float* out = (float*)d_out;

    float* h  = (float*)d_ws;                 // [NN, DD]
    float* hl = h  + (size_t)NN * DD;         // [NN, DD]
    float* hr = hl + (size_t)NN * DD;         // [NN, DD]
    float* g  = hr + (size_t)NN * DD;         // [BBATCH, DD]
    float* EB = g  + (size_t)BBATCH * DD;     // [CC, DD]

    dim3 blk(256);

    k_in_proj<<<dim3(NN / 16), blk, 0, stream>>>(x, Win, bin, h);

    for (int l = 0; l < 3; ++l) {
        k_proj<<<dim3(NN / 16), blk, 0, stream>>>(h,
            Wl + (size_t)l * DD * DD, Wr + (size_t)l * DD * DD, hl, hr);
        k_edges<<<dim3(BBATCH), blk, 0, stream>>>(hl, hr, att + (size_t)l * DD, h);
    }

    k_readout<<<dim3(BBATCH), blk, 0, stream>>>(h, g);
    k_eb<<<dim3(CC), blk, 0, stream>>>(Erecv, Ws1, EB);
    k_head<<<dim3(BBATCH), blk, 0, stream>>>(g, Wr1, br1, Wr2, br2,
                                             Ws1, bs1, Ws2, bs2, EB, out);
}